// Round 9
// baseline (208.583 us; speedup 1.0000x reference)
//
#include <hip/hip_runtime.h>
#include <hip/hip_bf16.h>
#include <math.h>

#define BB 4
#define LL 5
#define HSZ 32
#define WSZ 32
#define PP (HSZ*WSZ)   // 1024
#define CC 256
#define MM 8
#define DD 32
#define II 256
#define TT 2
#define NTOK (BB*PP*LL*II)   // 5,242,880
#define TILE_ELEMS 8192      // 32 pixels x 256 chans, bf16 ELEMENTS (16 KB)
#define SCALE 0.17677669529663687f  // 1/sqrt(32)

typedef short bf16x8 __attribute__((ext_vector_type(8)));
typedef float f32x4 __attribute__((ext_vector_type(4)));

static __device__ __forceinline__ ushort f2bf(float f) {
    unsigned u = __float_as_uint(f);
    unsigned r = (u + 0x7fffu + ((u >> 16) & 1u)) >> 16;   // RNE
    return (ushort)r;
}
static __device__ __forceinline__ float bf2f(ushort u) {
    return __uint_as_float(((unsigned)u) << 16);
}

// ---------------------------------------------------------------------------
// k_fold: merged weight-prep + LayerNorm/pack (R2 verified version).
// DIAGNOSTIC (resubmit of R8; container died before it ran): launched x5
// (idempotent) to measure its true cost -- the last unmeasured kernel.
// ---------------------------------------------------------------------------
__global__ __launch_bounds__(256) void k_fold(
    const float* __restrict__ Wq, const float* __restrict__ Wv,
    const float* __restrict__ Wk, const float* __restrict__ Wa,
    const float* __restrict__ bq, const float* __restrict__ bv,
    const float* __restrict__ rel_att, const float* __restrict__ rel_msg,
    const float* __restrict__ x,
    const float* __restrict__ lnw, const float* __restrict__ lnb,
    ushort* __restrict__ packW, float* __restrict__ bEff,
    ushort* __restrict__ xnPack)
{
    __shared__ float As[1024];
    __shared__ ushort Apack[8192];
    const int blk = blockIdx.x;
    const int tid = threadIdx.x;

    if (blk < 64) {
        const int p  = blk >> 5;
        const int t  = (blk >> 4) & 1;
        const int ts = (blk >> 3) & 1;
        const int m  = blk & 7;
        const float* A = (p == 0)
            ? rel_att + (size_t)((t * 2 + ts) * 8 + m) * 1024
            : rel_msg + (size_t)((ts * 2 + t) * 8 + m) * 1024;
        for (int i = tid; i < 1024; i += 256) As[i] = A[i];
        __syncthreads();

        const float* W = ((p == 0) ? Wq : Wv) + (size_t)t * 65536;
        const int k = tid;
        float wrow[32];
        #pragma unroll
        for (int u = 0; u < 8; ++u)
            *(float4*)&wrow[u * 4] = *(const float4*)&W[k * 256 + m * 32 + u * 4];

        const int slot = (p == 0 ? 0 : 4) + t * 2 + ts;
        ushort* base = packW + (size_t)slot * 65536;
        const int kt = k >> 5, j = k & 7, lq = ((k >> 3) & 3) * 16;
        #pragma unroll
        for (int q = 0; q < 32; ++q) {
            float acc = 0.f;
            #pragma unroll
            for (int pp = 0; pp < 32; ++pp) acc += wrow[pp] * As[pp * 32 + q];
            const int nt = m * 2 + (q >> 4);
            const int lane = lq + (q & 15);
            base[(size_t)((nt * 8 + kt) * 64 + lane) * 8 + j] = f2bf(acc);
        }
        if (tid < 32) {
            const int q = tid;
            const float* bi = ((p == 0) ? bq : bv) + t * 256 + m * 32;
            float acc = 0.f;
            #pragma unroll
            for (int pp = 0; pp < 32; ++pp) acc += bi[pp] * As[pp * 32 + q];
            bEff[(p ? 1024 : 0) + (t * 2 + ts) * 256 + m * 32 + q] = acc;
        }
    } else if (blk < 192) {
        const int idx = blk - 64;
        const int which = idx >> 6;              // 0 = Wk, 1 = Wa
        const int gi = (idx & 63) * 256 + tid;   // 0..16383
        const int t = gi >> 13;
        const int sub = gi & 8191;
        const float* src = ((which == 0) ? Wk : Wa) + (size_t)t * 65536;
        const int slot = (which == 0 ? 8 : 10) + t;
        const int nt = sub >> 9, kt = (sub >> 6) & 7, lane = sub & 63;
        const int k0 = kt * 32 + (lane >> 4) * 8;
        const int n  = nt * 16 + (lane & 15);
        ushort h[8];
        #pragma unroll
        for (int j = 0; j < 8; ++j) h[j] = f2bf(src[(size_t)(k0 + j) * 256 + n]);
        uint4 o;
        o.x = (unsigned)h[0] | ((unsigned)h[1] << 16);
        o.y = (unsigned)h[2] | ((unsigned)h[3] << 16);
        o.z = (unsigned)h[4] | ((unsigned)h[5] << 16);
        o.w = (unsigned)h[6] | ((unsigned)h[7] << 16);
        *(uint4*)(packW + (size_t)slot * 65536 + (size_t)sub * 8) = o;
    } else {
        const int lblk = blk - 192;
        const int bl  = lblk >> 5;
        const int pt  = lblk & 31;
        const int p0  = pt * 32;

        const int r  = tid >> 3;     // 0..31 pixel row
        const int jj = tid & 7;      // 8 threads/row, 32 chans each
        const float* xrow = x + ((size_t)bl * PP + p0 + r) * CC;
        float4 xv[8];
        float s1 = 0.f, s2 = 0.f;
        #pragma unroll
        for (int u = 0; u < 8; ++u) {
            xv[u] = *(const float4*)(xrow + jj * 32 + u * 4);
            s1 += xv[u].x + xv[u].y + xv[u].z + xv[u].w;
            s2 += xv[u].x * xv[u].x + xv[u].y * xv[u].y + xv[u].z * xv[u].z + xv[u].w * xv[u].w;
        }
        s1 += __shfl_xor(s1, 1); s1 += __shfl_xor(s1, 2); s1 += __shfl_xor(s1, 4);
        s2 += __shfl_xor(s2, 1); s2 += __shfl_xor(s2, 2); s2 += __shfl_xor(s2, 4);
        const float mu   = s1 * (1.0f / 256.0f);
        const float var  = s2 * (1.0f / 256.0f) - mu * mu;
        const float rstd = rsqrtf(var + 1e-5f);

        const int mt_r = r >> 4, rm = r & 15;
        #pragma unroll
        for (int u = 0; u < 8; ++u) {
            const int c0 = jj * 32 + u * 4;
            const float4 g  = *(const float4*)(lnw + c0);
            const float4 bt = *(const float4*)(lnb + c0);
            const ushort h0 = f2bf((xv[u].x - mu) * rstd * g.x + bt.x);
            const ushort h1 = f2bf((xv[u].y - mu) * rstd * g.y + bt.y);
            const ushort h2 = f2bf((xv[u].z - mu) * rstd * g.z + bt.z);
            const ushort h3 = f2bf((xv[u].w - mu) * rstd * g.w + bt.w);
            uint2 w2;
            w2.x = (unsigned)h0 | ((unsigned)h1 << 16);
            w2.y = (unsigned)h2 | ((unsigned)h3 << 16);
            const int kt   = c0 >> 5;
            const int lsub = rm + (((c0 >> 3) & 3) << 4);
            const int j0   = c0 & 7;
            *(uint2*)&Apack[(((mt_r * 8 + kt) * 64 + lsub) << 3) + j0] = w2;
        }
        __syncthreads();

        const size_t tbase = (size_t)lblk * TILE_ELEMS;
        #pragma unroll
        for (int u = 0; u < 4; ++u) {
            const int ch = (tid + u * 256) * 8;
            *(uint4*)&xnPack[tbase + ch] = *(const uint4*)&Apack[ch];
        }
    }
}

// ---------------------------------------------------------------------------
// k_proj: 5 per-type projections, weight-stationary B in registers.
// (R2 verified version, unchanged.)
// ---------------------------------------------------------------------------
__global__ __launch_bounds__(256) void k_proj(
    const ushort* __restrict__ xnPack, const float* __restrict__ prior,
    const ushort* __restrict__ packW, const float* __restrict__ bEff,
    const float* __restrict__ bk,
    ushort* __restrict__ qw0, ushort* __restrict__ qw1, ushort* __restrict__ kkO,
    ushort* __restrict__ vm0, ushort* __restrict__ vm1)
{
    __shared__ ushort As[8192];   // 16 KB, one A-tile in frag order

    const int tid  = threadIdx.x;
    const int blk  = blockIdx.x;
    const int mat  = blk / 640;
    const int rem  = blk - mat * 640;
    const int bl   = rem >> 5;
    const int sub  = rem & 31;
    const int pg   = sub >> 1;      // 16 groups of 2 tiles
    const int half = sub & 1;       // col half (128 cols)
    const int t    = (int)prior[(size_t)bl * (PP * 3) + 2];

    int slot; const float* bias;
    if (mat < 2)       { slot = t * 2 + mat;           bias = bEff + slot * 256; }
    else if (mat == 2) { slot = 8 + t;                 bias = bk + t * 256; }
    else               { slot = 4 + t * 2 + (mat - 3); bias = bEff + 1024 + (t * 2 + (mat - 3)) * 256; }
    ushort* dst = (mat == 0) ? qw0 : (mat == 1) ? qw1 : (mat == 2) ? kkO : (mat == 3) ? vm0 : vm1;

    const int wv = tid >> 6, lane = tid & 63;

    const ushort* Bp = packW + (size_t)slot * 65536;
    bf16x8 bfr[8][2];
    #pragma unroll
    for (int kt = 0; kt < 8; ++kt)
        #pragma unroll
        for (int nn = 0; nn < 2; ++nn) {
            const int ntg = half * 8 + wv * 2 + nn;
            bfr[kt][nn] = *(const bf16x8*)&Bp[(size_t)((ntg * 8 + kt) * 64 + lane) * 8];
        }

    const int cl = lane & 15, rq = lane >> 4;
    const int colA = half * 128 + wv * 32 + cl;
    const int colB = colA + 16;
    const float biasA = bias[colA], biasB = bias[colB];

    #pragma unroll 1
    for (int tl = 0; tl < 2; ++tl) {
        const int pt = pg * 2 + tl;
        const size_t tbase = (size_t)(bl * 32 + pt) * TILE_ELEMS;
        __syncthreads();   // As reads of previous tile done
        #pragma unroll
        for (int u = 0; u < 4; ++u) {
            const int ch = (tid + u * 256) * 8;
            *(uint4*)&As[ch] = *(const uint4*)&xnPack[tbase + ch];
        }
        __syncthreads();

        f32x4 acc[2][2];
        #pragma unroll
        for (int mt = 0; mt < 2; ++mt)
            #pragma unroll
            for (int nn = 0; nn < 2; ++nn)
                acc[mt][nn] = (f32x4){0.f, 0.f, 0.f, 0.f};

        #pragma unroll
        for (int kt = 0; kt < 8; ++kt) {
            const bf16x8 a0 = *(const bf16x8*)&As[((0 * 8 + kt) * 64 + lane) << 3];
            const bf16x8 a1 = *(const bf16x8*)&As[((1 * 8 + kt) * 64 + lane) << 3];
            acc[0][0] = __builtin_amdgcn_mfma_f32_16x16x32_bf16(a0, bfr[kt][0], acc[0][0], 0, 0, 0);
            acc[0][1] = __builtin_amdgcn_mfma_f32_16x16x32_bf16(a0, bfr[kt][1], acc[0][1], 0, 0, 0);
            acc[1][0] = __builtin_amdgcn_mfma_f32_16x16x32_bf16(a1, bfr[kt][0], acc[1][0], 0, 0, 0);
            acc[1][1] = __builtin_amdgcn_mfma_f32_16x16x32_bf16(a1, bfr[kt][1], acc[1][1], 0, 0, 0);
        }

        const int p0 = pt * 32;
        #pragma unroll
        for (int mt = 0; mt < 2; ++mt) {
            const int row0 = p0 + mt * 16 + rq * 4;
            #pragma unroll
            for (int r2 = 0; r2 < 4; ++r2) {
                const size_t rb = ((size_t)bl * PP + row0 + r2) * II;
                dst[rb + colA] = f2bf(acc[mt][0][r2] + biasA);
                dst[rb + colB] = f2bf(acc[mt][1][r2] + biasB);
            }
        }
    }
}

// ---------------------------------------------------------------------------
// k_attn_out v2: merged col-halves -- 256 blocks x 512 threads (8 waves).
// (R7 verified version, unchanged.)
// ---------------------------------------------------------------------------
__global__ __launch_bounds__(512) void k_attn_out(
    const ushort* __restrict__ qw0, const ushort* __restrict__ qw1,
    const ushort* __restrict__ kkI,
    const ushort* __restrict__ vm0, const ushort* __restrict__ vm1,
    const int* __restrict__ mask, const float* __restrict__ prior,
    const ushort* __restrict__ packW, const float* __restrict__ ba,
    float* __restrict__ out)
{
    __shared__ ushort aoS[5 * 16 * 264];   // 42.2 KB
    __shared__ float obufF[16 * 260];      // 16.6 KB

    const int tid  = threadIdx.x;
    const int blk  = blockIdx.x;            // 0..255
    const int b    = blk >> 6;
    const int pg   = blk & 63;
    const int p0   = pg * 16;
    const int wv   = tid >> 6, lane = tid & 63;
    const int c0   = lane * 4;

    int ty[5];
    #pragma unroll
    for (int l = 0; l < 5; ++l)
        ty[l] = (int)prior[(size_t)(b * 5 + l) * (PP * 3) + 2];

    // ---- Phase A: 2 sites per wave, all loads issued up front ----
    {
        ushort4 rq0[2][5], rq1[2][5], rkv[2][5], rv0[2][5], rv1[2][5];
        #pragma unroll
        for (int it = 0; it < 2; ++it) {
            const int pix = p0 + wv * 2 + it;
            #pragma unroll
            for (int l = 0; l < 5; ++l) {
                const size_t base = (((size_t)(b * 5 + l) << 10) + pix) * II + c0;
                rq0[it][l] = *(const ushort4*)(qw0 + base);
                rq1[it][l] = *(const ushort4*)(qw1 + base);
                rkv[it][l] = *(const ushort4*)(kkI + base);
                rv0[it][l] = *(const ushort4*)(vm0 + base);
                rv1[it][l] = *(const ushort4*)(vm1 + base);
            }
        }

        #pragma unroll
        for (int it = 0; it < 2; ++it) {
            const int sl   = wv * 2 + it;
            const int pix  = p0 + sl;
            const int site = b * 1024 + pix;
            const int usite = __builtin_amdgcn_readfirstlane(site);

            int mv[5][5];
            #pragma unroll
            for (int i = 0; i < 5; ++i)
                #pragma unroll
                for (int j = 0; j < 5; ++j)
                    mv[i][j] = mask[(size_t)usite * 25 + i * 5 + j];

            float qf[2][5][4], kf[5][4];
            #pragma unroll
            for (int l = 0; l < 5; ++l) {
                qf[0][l][0] = bf2f(rq0[it][l].x); qf[0][l][1] = bf2f(rq0[it][l].y);
                qf[0][l][2] = bf2f(rq0[it][l].z); qf[0][l][3] = bf2f(rq0[it][l].w);
                qf[1][l][0] = bf2f(rq1[it][l].x); qf[1][l][1] = bf2f(rq1[it][l].y);
                qf[1][l][2] = bf2f(rq1[it][l].z); qf[1][l][3] = bf2f(rq1[it][l].w);
                kf[l][0]    = bf2f(rkv[it][l].x); kf[l][1]    = bf2f(rkv[it][l].y);
                kf[l][2]    = bf2f(rkv[it][l].z); kf[l][3]    = bf2f(rkv[it][l].w);
            }

            float s[5][5];
            #pragma unroll
            for (int j = 0; j < 5; ++j) {
                if (ty[j]) {
                    #pragma unroll
                    for (int i = 0; i < 5; ++i)
                        s[i][j] = qf[1][i][0] * kf[j][0] + qf[1][i][1] * kf[j][1]
                                + qf[1][i][2] * kf[j][2] + qf[1][i][3] * kf[j][3];
                } else {
                    #pragma unroll
                    for (int i = 0; i < 5; ++i)
                        s[i][j] = qf[0][i][0] * kf[j][0] + qf[0][i][1] * kf[j][1]
                                + qf[0][i][2] * kf[j][2] + qf[0][i][3] * kf[j][3];
                }
            }
            #pragma unroll
            for (int i = 0; i < 5; ++i)
                #pragma unroll
                for (int j = 0; j < 5; ++j) s[i][j] += __shfl_xor(s[i][j], 1);
            #pragma unroll
            for (int i = 0; i < 5; ++i)
                #pragma unroll
                for (int j = 0; j < 5; ++j) s[i][j] += __shfl_xor(s[i][j], 2);
            #pragma unroll
            for (int i = 0; i < 5; ++i)
                #pragma unroll
                for (int j = 0; j < 5; ++j) s[i][j] += __shfl_xor(s[i][j], 4);

            float vf[2][5][4];
            #pragma unroll
            for (int l = 0; l < 5; ++l) {
                vf[0][l][0] = bf2f(rv0[it][l].x); vf[0][l][1] = bf2f(rv0[it][l].y);
                vf[0][l][2] = bf2f(rv0[it][l].z); vf[0][l][3] = bf2f(rv0[it][l].w);
                vf[1][l][0] = bf2f(rv1[it][l].x); vf[1][l][1] = bf2f(rv1[it][l].y);
                vf[1][l][2] = bf2f(rv1[it][l].z); vf[1][l][3] = bf2f(rv1[it][l].w);
            }

            #pragma unroll
            for (int i = 0; i < 5; ++i) {
                float lg[5];
                #pragma unroll
                for (int j = 0; j < 5; ++j)
                    lg[j] = mv[i][j] ? s[i][j] * SCALE : -1e9f;
                const float mx = fmaxf(fmaxf(fmaxf(lg[0], lg[1]), fmaxf(lg[2], lg[3])), lg[4]);
                float ex[5], sum = 0.f;
                #pragma unroll
                for (int j = 0; j < 5; ++j) { ex[j] = __expf(lg[j] - mx); sum += ex[j]; }
                const float rs = 1.0f / sum;
                float o0 = 0.f, o1 = 0.f, o2 = 0.f, o3 = 0.f;
                if (ty[i]) {
                    #pragma unroll
                    for (int j = 0; j < 5; ++j) {
                        o0 += ex[j] * vf[1][j][0]; o1 += ex[j] * vf[1][j][1];
                        o2 += ex[j] * vf[1][j][2]; o3 += ex[j] * vf[1][j][3];
                    }
                } else {
                    #pragma unroll
                    for (int j = 0; j < 5; ++j) {
                        o0 += ex[j] * vf[0][j][0]; o1 += ex[j] * vf[0][j][1];
                        o2 += ex[j] * vf[0][j][2]; o3 += ex[j] * vf[0][j][3];
                    }
                }
                o0 *= rs; o1 *= rs; o2 *= rs; o3 *= rs;
                uint2 w2;
                w2.x = (unsigned)f2bf(o0) | ((unsigned)f2bf(o1) << 16);
                w2.y = (unsigned)f2bf(o2) | ((unsigned)f2bf(o3) << 16);
                *(uint2*)&aoS[(i * 16 + sl) * 264 + c0] = w2;
            }
        }
    }
    __syncthreads();

    // ---- Phase B: 8 waves = 2 halves x 4 col-roles ----
    const int half = wv >> 2;
    const int wv2  = wv & 3;
    const int cl = lane & 15, rq = lane >> 4;
    const int rowA = lane & 15;
    const int ksub = (lane >> 4) * 8;
    const int colL_A = wv2 * 32 + cl;           // local col within the 128-half
    const int colL_B = colL_A + 16;

    #pragma unroll 1
    for (int l = 0; l < 5; ++l) {
        const int t = ty[l];
        const ushort* Bp = packW + (size_t)(10 + t) * 65536;
        bf16x8 bfr[8][2];
        #pragma unroll
        for (int kt = 0; kt < 8; ++kt)
            #pragma unroll
            for (int nn = 0; nn < 2; ++nn) {
                const int ntg = half * 8 + wv2 * 2 + nn;
                bfr[kt][nn] = *(const bf16x8*)&Bp[(size_t)((ntg * 8 + kt) * 64 + lane) * 8];
            }

        f32x4 acc[2];
        acc[0] = (f32x4){0.f, 0.f, 0.f, 0.f};
        acc[1] = (f32x4){0.f, 0.f, 0.f, 0.f};

        const ushort* aRow = &aoS[(l * 16 + rowA) * 264 + ksub];
        #pragma unroll
        for (int kt = 0; kt < 8; ++kt) {
            const bf16x8 a0 = *(const bf16x8*)(aRow + kt * 32);
            acc[0] = __builtin_amdgcn_mfma_f32_16x16x32_bf16(a0, bfr[kt][0], acc[0], 0, 0, 0);
            acc[1] = __builtin_amdgcn_mfma_f32_16x16x32_bf16(a0, bfr[kt][1], acc[1], 0, 0, 0);
        }

        const float biasA = ba[t * CC + half * 128 + colL_A];
        const float biasB = ba[t * CC + half * 128 + colL_B];

        __syncthreads();   // previous l's obuf reads done
        #pragma unroll
        for (int r2 = 0; r2 < 4; ++r2) {
            obufF[(rq * 4 + r2) * 260 + half * 128 + colL_A] = acc[0][r2] + biasA;
            obufF[(rq * 4 + r2) * 260 + half * 128 + colL_B] = acc[1][r2] + biasB;
        }
        __syncthreads();

        // coalesced store: 16 rows x 64 float4-chunks = 1024 stores
        #pragma unroll
        for (int k2 = 0; k2 < 2; ++k2) {
            const int id  = tid + k2 * 512;
            const int row = id >> 6;            // 0..15
            const int ch  = (id & 63) * 4;      // float4 chunk within 256 cols
            const float4 v4 = *(const float4*)&obufF[row * 260 + ch];
            *(float4*)(out + ((size_t)(b * LL + l) * PP + p0 + row) * CC + ch) = v4;
        }
    }
}

// ---------------------------------------------------------------------------
// DIAGNOSTIC (resubmit): k_fold x5 (idempotent). dur ~= 149.3 + 4F + 4 gaps.
// F >= 42 -> k_fold surfaces in top-5 with counters.
// ---------------------------------------------------------------------------
extern "C" void kernel_launch(void* const* d_in, const int* in_sizes, int n_in,
                              void* d_out, int out_size, void* d_ws, size_t ws_size,
                              hipStream_t stream) {
    const float* x       = (const float*)d_in[0];
    const int*   mask    = (const int*)d_in[1];
    const float* prior   = (const float*)d_in[2];
    const float* lnw     = (const float*)d_in[3];
    const float* lnb     = (const float*)d_in[4];
    const float* Wq      = (const float*)d_in[5];
    const float* bq      = (const float*)d_in[6];
    const float* Wk      = (const float*)d_in[7];
    const float* bk      = (const float*)d_in[8];
    const float* Wv      = (const float*)d_in[9];
    const float* bv      = (const float*)d_in[10];
    const float* Wa      = (const float*)d_in[11];
    const float* ba      = (const float*)d_in[12];
    const float* rel_att = (const float*)d_in[13];
    const float* rel_msg = (const float*)d_in[14];
    float* out = (float*)d_out;

    ushort* qw0    = (ushort*)d_ws;
    ushort* qw1    = qw0 + NTOK;
    ushort* kko    = qw1 + NTOK;
    ushort* vm0    = kko + NTOK;
    ushort* vm1    = vm0 + NTOK;
    ushort* xnPack = vm1 + NTOK;
    ushort* packW  = xnPack + NTOK;                 // 12 * 65536 bf16
    float*  bEff   = (float*)(packW + 12 * 65536);  // 2048 fp32

    for (int r = 0; r < 5; ++r)
        hipLaunchKernelGGL(k_fold, dim3(832), dim3(256), 0, stream,
                           Wq, Wv, Wk, Wa, bq, bv, rel_att, rel_msg,
                           x, lnw, lnb, packW, bEff, xnPack);
    hipLaunchKernelGGL(k_proj, dim3(3200), dim3(256), 0, stream,
                       xnPack, prior, packW, bEff, bk, qw0, qw1, kko, vm0, vm1);
    hipLaunchKernelGGL(k_attn_out, dim3(256), dim3(512), 0, stream,
                       qw0, qw1, kko, vm0, vm1, mask, prior, packW, ba, out);
}

// Round 10
// 154.155 us; speedup vs baseline: 1.3531x; 1.3531x over previous
//
#include <hip/hip_runtime.h>
#include <hip/hip_bf16.h>
#include <math.h>

#define BB 4
#define LL 5
#define HSZ 32
#define WSZ 32
#define PP (HSZ*WSZ)   // 1024
#define CC 256
#define MM 8
#define DD 32
#define II 256
#define TT 2
#define NTOK (BB*PP*LL*II)   // 5,242,880
#define TILE_ELEMS 8192      // 32 pixels x 256 chans, bf16 ELEMENTS (16 KB)
#define SCALE 0.17677669529663687f  // 1/sqrt(32)

typedef short bf16x8 __attribute__((ext_vector_type(8)));
typedef float f32x4 __attribute__((ext_vector_type(4)));

static __device__ __forceinline__ ushort f2bf(float f) {
    unsigned u = __float_as_uint(f);
    unsigned r = (u + 0x7fffu + ((u >> 16) & 1u)) >> 16;   // RNE
    return (ushort)r;
}
static __device__ __forceinline__ float bf2f(ushort u) {
    return __uint_as_float(((unsigned)u) << 16);
}

// ---------------------------------------------------------------------------
// k_fold: merged weight-prep + LayerNorm/pack (R2 verified version).
// Measured R9: ~13 us.
// ---------------------------------------------------------------------------
__global__ __launch_bounds__(256) void k_fold(
    const float* __restrict__ Wq, const float* __restrict__ Wv,
    const float* __restrict__ Wk, const float* __restrict__ Wa,
    const float* __restrict__ bq, const float* __restrict__ bv,
    const float* __restrict__ rel_att, const float* __restrict__ rel_msg,
    const float* __restrict__ x,
    const float* __restrict__ lnw, const float* __restrict__ lnb,
    ushort* __restrict__ packW, float* __restrict__ bEff,
    ushort* __restrict__ xnPack)
{
    __shared__ float As[1024];
    __shared__ ushort Apack[8192];
    const int blk = blockIdx.x;
    const int tid = threadIdx.x;

    if (blk < 64) {
        const int p  = blk >> 5;
        const int t  = (blk >> 4) & 1;
        const int ts = (blk >> 3) & 1;
        const int m  = blk & 7;
        const float* A = (p == 0)
            ? rel_att + (size_t)((t * 2 + ts) * 8 + m) * 1024
            : rel_msg + (size_t)((ts * 2 + t) * 8 + m) * 1024;
        for (int i = tid; i < 1024; i += 256) As[i] = A[i];
        __syncthreads();

        const float* W = ((p == 0) ? Wq : Wv) + (size_t)t * 65536;
        const int k = tid;
        float wrow[32];
        #pragma unroll
        for (int u = 0; u < 8; ++u)
            *(float4*)&wrow[u * 4] = *(const float4*)&W[k * 256 + m * 32 + u * 4];

        const int slot = (p == 0 ? 0 : 4) + t * 2 + ts;
        ushort* base = packW + (size_t)slot * 65536;
        const int kt = k >> 5, j = k & 7, lq = ((k >> 3) & 3) * 16;
        #pragma unroll
        for (int q = 0; q < 32; ++q) {
            float acc = 0.f;
            #pragma unroll
            for (int pp = 0; pp < 32; ++pp) acc += wrow[pp] * As[pp * 32 + q];
            const int nt = m * 2 + (q >> 4);
            const int lane = lq + (q & 15);
            base[(size_t)((nt * 8 + kt) * 64 + lane) * 8 + j] = f2bf(acc);
        }
        if (tid < 32) {
            const int q = tid;
            const float* bi = ((p == 0) ? bq : bv) + t * 256 + m * 32;
            float acc = 0.f;
            #pragma unroll
            for (int pp = 0; pp < 32; ++pp) acc += bi[pp] * As[pp * 32 + q];
            bEff[(p ? 1024 : 0) + (t * 2 + ts) * 256 + m * 32 + q] = acc;
        }
    } else if (blk < 192) {
        const int idx = blk - 64;
        const int which = idx >> 6;              // 0 = Wk, 1 = Wa
        const int gi = (idx & 63) * 256 + tid;   // 0..16383
        const int t = gi >> 13;
        const int sub = gi & 8191;
        const float* src = ((which == 0) ? Wk : Wa) + (size_t)t * 65536;
        const int slot = (which == 0 ? 8 : 10) + t;
        const int nt = sub >> 9, kt = (sub >> 6) & 7, lane = sub & 63;
        const int k0 = kt * 32 + (lane >> 4) * 8;
        const int n  = nt * 16 + (lane & 15);
        ushort h[8];
        #pragma unroll
        for (int j = 0; j < 8; ++j) h[j] = f2bf(src[(size_t)(k0 + j) * 256 + n]);
        uint4 o;
        o.x = (unsigned)h[0] | ((unsigned)h[1] << 16);
        o.y = (unsigned)h[2] | ((unsigned)h[3] << 16);
        o.z = (unsigned)h[4] | ((unsigned)h[5] << 16);
        o.w = (unsigned)h[6] | ((unsigned)h[7] << 16);
        *(uint4*)(packW + (size_t)slot * 65536 + (size_t)sub * 8) = o;
    } else {
        const int lblk = blk - 192;
        const int bl  = lblk >> 5;
        const int pt  = lblk & 31;
        const int p0  = pt * 32;

        const int r  = tid >> 3;     // 0..31 pixel row
        const int jj = tid & 7;      // 8 threads/row, 32 chans each
        const float* xrow = x + ((size_t)bl * PP + p0 + r) * CC;
        float4 xv[8];
        float s1 = 0.f, s2 = 0.f;
        #pragma unroll
        for (int u = 0; u < 8; ++u) {
            xv[u] = *(const float4*)(xrow + jj * 32 + u * 4);
            s1 += xv[u].x + xv[u].y + xv[u].z + xv[u].w;
            s2 += xv[u].x * xv[u].x + xv[u].y * xv[u].y + xv[u].z * xv[u].z + xv[u].w * xv[u].w;
        }
        s1 += __shfl_xor(s1, 1); s1 += __shfl_xor(s1, 2); s1 += __shfl_xor(s1, 4);
        s2 += __shfl_xor(s2, 1); s2 += __shfl_xor(s2, 2); s2 += __shfl_xor(s2, 4);
        const float mu   = s1 * (1.0f / 256.0f);
        const float var  = s2 * (1.0f / 256.0f) - mu * mu;
        const float rstd = rsqrtf(var + 1e-5f);

        const int mt_r = r >> 4, rm = r & 15;
        #pragma unroll
        for (int u = 0; u < 8; ++u) {
            const int c0 = jj * 32 + u * 4;
            const float4 g  = *(const float4*)(lnw + c0);
            const float4 bt = *(const float4*)(lnb + c0);
            const ushort h0 = f2bf((xv[u].x - mu) * rstd * g.x + bt.x);
            const ushort h1 = f2bf((xv[u].y - mu) * rstd * g.y + bt.y);
            const ushort h2 = f2bf((xv[u].z - mu) * rstd * g.z + bt.z);
            const ushort h3 = f2bf((xv[u].w - mu) * rstd * g.w + bt.w);
            uint2 w2;
            w2.x = (unsigned)h0 | ((unsigned)h1 << 16);
            w2.y = (unsigned)h2 | ((unsigned)h3 << 16);
            const int kt   = c0 >> 5;
            const int lsub = rm + (((c0 >> 3) & 3) << 4);
            const int j0   = c0 & 7;
            *(uint2*)&Apack[(((mt_r * 8 + kt) * 64 + lsub) << 3) + j0] = w2;
        }
        __syncthreads();

        const size_t tbase = (size_t)lblk * TILE_ELEMS;
        #pragma unroll
        for (int u = 0; u < 4; ++u) {
            const int ch = (tid + u * 256) * 8;
            *(uint4*)&xnPack[tbase + ch] = *(const uint4*)&Apack[ch];
        }
    }
}

// ---------------------------------------------------------------------------
// k_proj: 5 per-type projections, weight-stationary B in registers.
// (R2 verified version, unchanged. Measured R6: ~6 us.)
// ---------------------------------------------------------------------------
__global__ __launch_bounds__(256) void k_proj(
    const ushort* __restrict__ xnPack, const float* __restrict__ prior,
    const ushort* __restrict__ packW, const float* __restrict__ bEff,
    const float* __restrict__ bk,
    ushort* __restrict__ qw0, ushort* __restrict__ qw1, ushort* __restrict__ kkO,
    ushort* __restrict__ vm0, ushort* __restrict__ vm1)
{
    __shared__ ushort As[8192];   // 16 KB, one A-tile in frag order

    const int tid  = threadIdx.x;
    const int blk  = blockIdx.x;
    const int mat  = blk / 640;
    const int rem  = blk - mat * 640;
    const int bl   = rem >> 5;
    const int sub  = rem & 31;
    const int pg   = sub >> 1;      // 16 groups of 2 tiles
    const int half = sub & 1;       // col half (128 cols)
    const int t    = (int)prior[(size_t)bl * (PP * 3) + 2];

    int slot; const float* bias;
    if (mat < 2)       { slot = t * 2 + mat;           bias = bEff + slot * 256; }
    else if (mat == 2) { slot = 8 + t;                 bias = bk + t * 256; }
    else               { slot = 4 + t * 2 + (mat - 3); bias = bEff + 1024 + (t * 2 + (mat - 3)) * 256; }
    ushort* dst = (mat == 0) ? qw0 : (mat == 1) ? qw1 : (mat == 2) ? kkO : (mat == 3) ? vm0 : vm1;

    const int wv = tid >> 6, lane = tid & 63;

    const ushort* Bp = packW + (size_t)slot * 65536;
    bf16x8 bfr[8][2];
    #pragma unroll
    for (int kt = 0; kt < 8; ++kt)
        #pragma unroll
        for (int nn = 0; nn < 2; ++nn) {
            const int ntg = half * 8 + wv * 2 + nn;
            bfr[kt][nn] = *(const bf16x8*)&Bp[(size_t)((ntg * 8 + kt) * 64 + lane) * 8];
        }

    const int cl = lane & 15, rq = lane >> 4;
    const int colA = half * 128 + wv * 32 + cl;
    const int colB = colA + 16;
    const float biasA = bias[colA], biasB = bias[colB];

    #pragma unroll 1
    for (int tl = 0; tl < 2; ++tl) {
        const int pt = pg * 2 + tl;
        const size_t tbase = (size_t)(bl * 32 + pt) * TILE_ELEMS;
        __syncthreads();   // As reads of previous tile done
        #pragma unroll
        for (int u = 0; u < 4; ++u) {
            const int ch = (tid + u * 256) * 8;
            *(uint4*)&As[ch] = *(const uint4*)&xnPack[tbase + ch];
        }
        __syncthreads();

        f32x4 acc[2][2];
        #pragma unroll
        for (int mt = 0; mt < 2; ++mt)
            #pragma unroll
            for (int nn = 0; nn < 2; ++nn)
                acc[mt][nn] = (f32x4){0.f, 0.f, 0.f, 0.f};

        #pragma unroll
        for (int kt = 0; kt < 8; ++kt) {
            const bf16x8 a0 = *(const bf16x8*)&As[((0 * 8 + kt) * 64 + lane) << 3];
            const bf16x8 a1 = *(const bf16x8*)&As[((1 * 8 + kt) * 64 + lane) << 3];
            acc[0][0] = __builtin_amdgcn_mfma_f32_16x16x32_bf16(a0, bfr[kt][0], acc[0][0], 0, 0, 0);
            acc[0][1] = __builtin_amdgcn_mfma_f32_16x16x32_bf16(a0, bfr[kt][1], acc[0][1], 0, 0, 0);
            acc[1][0] = __builtin_amdgcn_mfma_f32_16x16x32_bf16(a1, bfr[kt][0], acc[1][0], 0, 0, 0);
            acc[1][1] = __builtin_amdgcn_mfma_f32_16x16x32_bf16(a1, bfr[kt][1], acc[1][1], 0, 0, 0);
        }

        const int p0 = pt * 32;
        #pragma unroll
        for (int mt = 0; mt < 2; ++mt) {
            const int row0 = p0 + mt * 16 + rq * 4;
            #pragma unroll
            for (int r2 = 0; r2 < 4; ++r2) {
                const size_t rb = ((size_t)bl * PP + row0 + r2) * II;
                dst[rb + colA] = f2bf(acc[mt][0][r2] + biasA);
                dst[rb + colB] = f2bf(acc[mt][1][r2] + biasB);
            }
        }
    }
}

// ---------------------------------------------------------------------------
// k_attn_out v3: 8-pixel groups -- 512 blocks x 512 threads, ~29 KB LDS
// -> 2 blocks/CU co-resident (16 waves/CU vs v2's 8): doubles the
// latency-hiding streams for the HBM q/k/v reads (v2 measured ~35 us,
// ~90% stall at 2 waves/SIMD).
//  Phase A: 8 waves x 1 site each, all 25 Q/K/V ushort4 loads up front.
//  Phase B: 8 waves = 2 halves x 4 col-roles; MFMA 16-row shaped on the
//           8 valid rows (A rows 8-15 read duplicated rows; their C rows
//           are never stored).
// ---------------------------------------------------------------------------
__global__ __launch_bounds__(512) void k_attn_out(
    const ushort* __restrict__ qw0, const ushort* __restrict__ qw1,
    const ushort* __restrict__ kkI,
    const ushort* __restrict__ vm0, const ushort* __restrict__ vm1,
    const int* __restrict__ mask, const float* __restrict__ prior,
    const ushort* __restrict__ packW, const float* __restrict__ ba,
    float* __restrict__ out)
{
    __shared__ ushort aoS[5 * 8 * 264];    // 21.1 KB
    __shared__ float obufF[8 * 260];       // 8.3 KB

    const int tid  = threadIdx.x;
    const int blk  = blockIdx.x;            // 0..511
    const int b    = blk >> 7;
    const int pg   = blk & 127;
    const int p0   = pg * 8;
    const int wv   = tid >> 6, lane = tid & 63;
    const int c0   = lane * 4;

    int ty[5];
    #pragma unroll
    for (int l = 0; l < 5; ++l)
        ty[l] = (int)prior[(size_t)(b * 5 + l) * (PP * 3) + 2];

    // ---- Phase A: 1 site per wave, all loads issued up front ----
    {
        const int sl   = wv;                 // local site 0..7
        const int pix  = p0 + sl;
        const int site = b * 1024 + pix;
        const int usite = __builtin_amdgcn_readfirstlane(site);

        ushort4 rq0[5], rq1[5], rkv[5], rv0[5], rv1[5];
        #pragma unroll
        for (int l = 0; l < 5; ++l) {
            const size_t base = (((size_t)(b * 5 + l) << 10) + pix) * II + c0;
            rq0[l] = *(const ushort4*)(qw0 + base);
            rq1[l] = *(const ushort4*)(qw1 + base);
            rkv[l] = *(const ushort4*)(kkI + base);
            rv0[l] = *(const ushort4*)(vm0 + base);
            rv1[l] = *(const ushort4*)(vm1 + base);
        }

        int mv[5][5];
        #pragma unroll
        for (int i = 0; i < 5; ++i)
            #pragma unroll
            for (int j = 0; j < 5; ++j)
                mv[i][j] = mask[(size_t)usite * 25 + i * 5 + j];

        float qf[2][5][4], kf[5][4];
        #pragma unroll
        for (int l = 0; l < 5; ++l) {
            qf[0][l][0] = bf2f(rq0[l].x); qf[0][l][1] = bf2f(rq0[l].y);
            qf[0][l][2] = bf2f(rq0[l].z); qf[0][l][3] = bf2f(rq0[l].w);
            qf[1][l][0] = bf2f(rq1[l].x); qf[1][l][1] = bf2f(rq1[l].y);
            qf[1][l][2] = bf2f(rq1[l].z); qf[1][l][3] = bf2f(rq1[l].w);
            kf[l][0]    = bf2f(rkv[l].x); kf[l][1]    = bf2f(rkv[l].y);
            kf[l][2]    = bf2f(rkv[l].z); kf[l][3]    = bf2f(rkv[l].w);
        }

        float s[5][5];
        #pragma unroll
        for (int j = 0; j < 5; ++j) {
            if (ty[j]) {
                #pragma unroll
                for (int i = 0; i < 5; ++i)
                    s[i][j] = qf[1][i][0] * kf[j][0] + qf[1][i][1] * kf[j][1]
                            + qf[1][i][2] * kf[j][2] + qf[1][i][3] * kf[j][3];
            } else {
                #pragma unroll
                for (int i = 0; i < 5; ++i)
                    s[i][j] = qf[0][i][0] * kf[j][0] + qf[0][i][1] * kf[j][1]
                            + qf[0][i][2] * kf[j][2] + qf[0][i][3] * kf[j][3];
            }
        }
        #pragma unroll
        for (int i = 0; i < 5; ++i)
            #pragma unroll
            for (int j = 0; j < 5; ++j) s[i][j] += __shfl_xor(s[i][j], 1);
        #pragma unroll
        for (int i = 0; i < 5; ++i)
            #pragma unroll
            for (int j = 0; j < 5; ++j) s[i][j] += __shfl_xor(s[i][j], 2);
        #pragma unroll
        for (int i = 0; i < 5; ++i)
            #pragma unroll
            for (int j = 0; j < 5; ++j) s[i][j] += __shfl_xor(s[i][j], 4);

        float vf[2][5][4];
        #pragma unroll
        for (int l = 0; l < 5; ++l) {
            vf[0][l][0] = bf2f(rv0[l].x); vf[0][l][1] = bf2f(rv0[l].y);
            vf[0][l][2] = bf2f(rv0[l].z); vf[0][l][3] = bf2f(rv0[l].w);
            vf[1][l][0] = bf2f(rv1[l].x); vf[1][l][1] = bf2f(rv1[l].y);
            vf[1][l][2] = bf2f(rv1[l].z); vf[1][l][3] = bf2f(rv1[l].w);
        }

        #pragma unroll
        for (int i = 0; i < 5; ++i) {
            float lg[5];
            #pragma unroll
            for (int j = 0; j < 5; ++j)
                lg[j] = mv[i][j] ? s[i][j] * SCALE : -1e9f;
            const float mx = fmaxf(fmaxf(fmaxf(lg[0], lg[1]), fmaxf(lg[2], lg[3])), lg[4]);
            float ex[5], sum = 0.f;
            #pragma unroll
            for (int j = 0; j < 5; ++j) { ex[j] = __expf(lg[j] - mx); sum += ex[j]; }
            const float rs = 1.0f / sum;
            float o0 = 0.f, o1 = 0.f, o2 = 0.f, o3 = 0.f;
            if (ty[i]) {
                #pragma unroll
                for (int j = 0; j < 5; ++j) {
                    o0 += ex[j] * vf[1][j][0]; o1 += ex[j] * vf[1][j][1];
                    o2 += ex[j] * vf[1][j][2]; o3 += ex[j] * vf[1][j][3];
                }
            } else {
                #pragma unroll
                for (int j = 0; j < 5; ++j) {
                    o0 += ex[j] * vf[0][j][0]; o1 += ex[j] * vf[0][j][1];
                    o2 += ex[j] * vf[0][j][2]; o3 += ex[j] * vf[0][j][3];
                }
            }
            o0 *= rs; o1 *= rs; o2 *= rs; o3 *= rs;
            uint2 w2;
            w2.x = (unsigned)f2bf(o0) | ((unsigned)f2bf(o1) << 16);
            w2.y = (unsigned)f2bf(o2) | ((unsigned)f2bf(o3) << 16);
            *(uint2*)&aoS[(i * 8 + sl) * 264 + c0] = w2;
        }
    }
    __syncthreads();

    // ---- Phase B: 8 waves = 2 halves x 4 col-roles; 8 valid rows ----
    const int half = wv >> 2;
    const int wv2  = wv & 3;
    const int cl = lane & 15, rq = lane >> 4;
    const int rowA8 = lane & 7;                 // valid A row (rows 8-15 dup)
    const int ksub = (lane >> 4) * 8;
    const int colL_A = wv2 * 32 + cl;           // local col within the 128-half
    const int colL_B = colL_A + 16;

    #pragma unroll 1
    for (int l = 0; l < 5; ++l) {
        const int t = ty[l];
        const ushort* Bp = packW + (size_t)(10 + t) * 65536;
        bf16x8 bfr[8][2];
        #pragma unroll
        for (int kt = 0; kt < 8; ++kt)
            #pragma unroll
            for (int nn = 0; nn < 2; ++nn) {
                const int ntg = half * 8 + wv2 * 2 + nn;
                bfr[kt][nn] = *(const bf16x8*)&Bp[(size_t)((ntg * 8 + kt) * 64 + lane) * 8];
            }

        f32x4 acc[2];
        acc[0] = (f32x4){0.f, 0.f, 0.f, 0.f};
        acc[1] = (f32x4){0.f, 0.f, 0.f, 0.f};

        const ushort* aRow = &aoS[(l * 8 + rowA8) * 264 + ksub];
        #pragma unroll
        for (int kt = 0; kt < 8; ++kt) {
            const bf16x8 a0 = *(const bf16x8*)(aRow + kt * 32);
            acc[0] = __builtin_amdgcn_mfma_f32_16x16x32_bf16(a0, bfr[kt][0], acc[0], 0, 0, 0);
            acc[1] = __builtin_amdgcn_mfma_f32_16x16x32_bf16(a0, bfr[kt][1], acc[1], 0, 0, 0);
        }

        const float biasA = ba[t * CC + half * 128 + colL_A];
        const float biasB = ba[t * CC + half * 128 + colL_B];

        __syncthreads();   // previous l's obuf reads done
        if (rq < 2) {
            #pragma unroll
            for (int r2 = 0; r2 < 4; ++r2) {
                obufF[(rq * 4 + r2) * 260 + half * 128 + colL_A] = acc[0][r2] + biasA;
                obufF[(rq * 4 + r2) * 260 + half * 128 + colL_B] = acc[1][r2] + biasB;
            }
        }
        __syncthreads();

        // coalesced store: 8 rows x 64 float4-chunks = 512 stores (one pass)
        const int row = tid >> 6;               // 0..7
        const int ch  = (tid & 63) * 4;         // float4 chunk within 256 cols
        const float4 v4 = *(const float4*)&obufF[row * 260 + ch];
        *(float4*)(out + ((size_t)(b * LL + l) * PP + p0 + row) * CC + ch) = v4;
    }
}

// ---------------------------------------------------------------------------
extern "C" void kernel_launch(void* const* d_in, const int* in_sizes, int n_in,
                              void* d_out, int out_size, void* d_ws, size_t ws_size,
                              hipStream_t stream) {
    const float* x       = (const float*)d_in[0];
    const int*   mask    = (const int*)d_in[1];
    const float* prior   = (const float*)d_in[2];
    const float* lnw     = (const float*)d_in[3];
    const float* lnb     = (const float*)d_in[4];
    const float* Wq      = (const float*)d_in[5];
    const float* bq      = (const float*)d_in[6];
    const float* Wk      = (const float*)d_in[7];
    const float* bk      = (const float*)d_in[8];
    const float* Wv      = (const float*)d_in[9];
    const float* bv      = (const float*)d_in[10];
    const float* Wa      = (const float*)d_in[11];
    const float* ba      = (const float*)d_in[12];
    const float* rel_att = (const float*)d_in[13];
    const float* rel_msg = (const float*)d_in[14];
    float* out = (float*)d_out;

    ushort* qw0    = (ushort*)d_ws;
    ushort* qw1    = qw0 + NTOK;
    ushort* kko    = qw1 + NTOK;
    ushort* vm0    = kko + NTOK;
    ushort* vm1    = vm0 + NTOK;
    ushort* xnPack = vm1 + NTOK;
    ushort* packW  = xnPack + NTOK;                 // 12 * 65536 bf16
    float*  bEff   = (float*)(packW + 12 * 65536);  // 2048 fp32

    hipLaunchKernelGGL(k_fold, dim3(832), dim3(256), 0, stream,
                       Wq, Wv, Wk, Wa, bq, bv, rel_att, rel_msg,
                       x, lnw, lnb, packW, bEff, xnPack);
    hipLaunchKernelGGL(k_proj, dim3(3200), dim3(256), 0, stream,
                       xnPack, prior, packW, bEff, bk, qw0, qw1, kko, vm0, vm1);
    hipLaunchKernelGGL(k_attn_out, dim3(512), dim3(512), 0, stream,
                       qw0, qw1, kko, vm0, vm1, mask, prior, packW, ba, out);
}

// Round 11
// 151.704 us; speedup vs baseline: 1.3749x; 1.0162x over previous
//
#include <hip/hip_runtime.h>
#include <hip/hip_bf16.h>
#include <math.h>

#define BB 4
#define LL 5
#define HSZ 32
#define WSZ 32
#define PP (HSZ*WSZ)   // 1024
#define CC 256
#define MM 8
#define DD 32
#define II 256
#define TT 2
#define NTOK (BB*PP*LL*II)   // 5,242,880
#define TILE_ELEMS 8192      // 32 pixels x 256 chans, bf16 ELEMENTS (16 KB)
#define SCALE 0.17677669529663687f  // 1/sqrt(32)

typedef short bf16x8 __attribute__((ext_vector_type(8)));
typedef float f32x4 __attribute__((ext_vector_type(4)));

static __device__ __forceinline__ ushort f2bf(float f) {
    unsigned u = __float_as_uint(f);
    unsigned r = (u + 0x7fffu + ((u >> 16) & 1u)) >> 16;   // RNE
    return (ushort)r;
}
static __device__ __forceinline__ float bf2f(ushort u) {
    return __uint_as_float(((unsigned)u) << 16);
}

// ---------------------------------------------------------------------------
// k_fold: merged weight-prep + LayerNorm/pack (R2 verified; measured ~13 us).
// ---------------------------------------------------------------------------
__global__ __launch_bounds__(256) void k_fold(
    const float* __restrict__ Wq, const float* __restrict__ Wv,
    const float* __restrict__ Wk, const float* __restrict__ Wa,
    const float* __restrict__ bq, const float* __restrict__ bv,
    const float* __restrict__ rel_att, const float* __restrict__ rel_msg,
    const float* __restrict__ x,
    const float* __restrict__ lnw, const float* __restrict__ lnb,
    ushort* __restrict__ packW, float* __restrict__ bEff,
    ushort* __restrict__ xnPack)
{
    __shared__ float As[1024];
    __shared__ ushort Apack[8192];
    const int blk = blockIdx.x;
    const int tid = threadIdx.x;

    if (blk < 64) {
        const int p  = blk >> 5;
        const int t  = (blk >> 4) & 1;
        const int ts = (blk >> 3) & 1;
        const int m  = blk & 7;
        const float* A = (p == 0)
            ? rel_att + (size_t)((t * 2 + ts) * 8 + m) * 1024
            : rel_msg + (size_t)((ts * 2 + t) * 8 + m) * 1024;
        for (int i = tid; i < 1024; i += 256) As[i] = A[i];
        __syncthreads();

        const float* W = ((p == 0) ? Wq : Wv) + (size_t)t * 65536;
        const int k = tid;
        float wrow[32];
        #pragma unroll
        for (int u = 0; u < 8; ++u)
            *(float4*)&wrow[u * 4] = *(const float4*)&W[k * 256 + m * 32 + u * 4];

        const int slot = (p == 0 ? 0 : 4) + t * 2 + ts;
        ushort* base = packW + (size_t)slot * 65536;
        const int kt = k >> 5, j = k & 7, lq = ((k >> 3) & 3) * 16;
        #pragma unroll
        for (int q = 0; q < 32; ++q) {
            float acc = 0.f;
            #pragma unroll
            for (int pp = 0; pp < 32; ++pp) acc += wrow[pp] * As[pp * 32 + q];
            const int nt = m * 2 + (q >> 4);
            const int lane = lq + (q & 15);
            base[(size_t)((nt * 8 + kt) * 64 + lane) * 8 + j] = f2bf(acc);
        }
        if (tid < 32) {
            const int q = tid;
            const float* bi = ((p == 0) ? bq : bv) + t * 256 + m * 32;
            float acc = 0.f;
            #pragma unroll
            for (int pp = 0; pp < 32; ++pp) acc += bi[pp] * As[pp * 32 + q];
            bEff[(p ? 1024 : 0) + (t * 2 + ts) * 256 + m * 32 + q] = acc;
        }
    } else if (blk < 192) {
        const int idx = blk - 64;
        const int which = idx >> 6;              // 0 = Wk, 1 = Wa
        const int gi = (idx & 63) * 256 + tid;   // 0..16383
        const int t = gi >> 13;
        const int sub = gi & 8191;
        const float* src = ((which == 0) ? Wk : Wa) + (size_t)t * 65536;
        const int slot = (which == 0 ? 8 : 10) + t;
        const int nt = sub >> 9, kt = (sub >> 6) & 7, lane = sub & 63;
        const int k0 = kt * 32 + (lane >> 4) * 8;
        const int n  = nt * 16 + (lane & 15);
        ushort h[8];
        #pragma unroll
        for (int j = 0; j < 8; ++j) h[j] = f2bf(src[(size_t)(k0 + j) * 256 + n]);
        uint4 o;
        o.x = (unsigned)h[0] | ((unsigned)h[1] << 16);
        o.y = (unsigned)h[2] | ((unsigned)h[3] << 16);
        o.z = (unsigned)h[4] | ((unsigned)h[5] << 16);
        o.w = (unsigned)h[6] | ((unsigned)h[7] << 16);
        *(uint4*)(packW + (size_t)slot * 65536 + (size_t)sub * 8) = o;
    } else {
        const int lblk = blk - 192;
        const int bl  = lblk >> 5;
        const int pt  = lblk & 31;
        const int p0  = pt * 32;

        const int r  = tid >> 3;     // 0..31 pixel row
        const int jj = tid & 7;      // 8 threads/row, 32 chans each
        const float* xrow = x + ((size_t)bl * PP + p0 + r) * CC;
        float4 xv[8];
        float s1 = 0.f, s2 = 0.f;
        #pragma unroll
        for (int u = 0; u < 8; ++u) {
            xv[u] = *(const float4*)(xrow + jj * 32 + u * 4);
            s1 += xv[u].x + xv[u].y + xv[u].z + xv[u].w;
            s2 += xv[u].x * xv[u].x + xv[u].y * xv[u].y + xv[u].z * xv[u].z + xv[u].w * xv[u].w;
        }
        s1 += __shfl_xor(s1, 1); s1 += __shfl_xor(s1, 2); s1 += __shfl_xor(s1, 4);
        s2 += __shfl_xor(s2, 1); s2 += __shfl_xor(s2, 2); s2 += __shfl_xor(s2, 4);
        const float mu   = s1 * (1.0f / 256.0f);
        const float var  = s2 * (1.0f / 256.0f) - mu * mu;
        const float rstd = rsqrtf(var + 1e-5f);

        const int mt_r = r >> 4, rm = r & 15;
        #pragma unroll
        for (int u = 0; u < 8; ++u) {
            const int c0 = jj * 32 + u * 4;
            const float4 g  = *(const float4*)(lnw + c0);
            const float4 bt = *(const float4*)(lnb + c0);
            const ushort h0 = f2bf((xv[u].x - mu) * rstd * g.x + bt.x);
            const ushort h1 = f2bf((xv[u].y - mu) * rstd * g.y + bt.y);
            const ushort h2 = f2bf((xv[u].z - mu) * rstd * g.z + bt.z);
            const ushort h3 = f2bf((xv[u].w - mu) * rstd * g.w + bt.w);
            uint2 w2;
            w2.x = (unsigned)h0 | ((unsigned)h1 << 16);
            w2.y = (unsigned)h2 | ((unsigned)h3 << 16);
            const int kt   = c0 >> 5;
            const int lsub = rm + (((c0 >> 3) & 3) << 4);
            const int j0   = c0 & 7;
            *(uint2*)&Apack[(((mt_r * 8 + kt) * 64 + lsub) << 3) + j0] = w2;
        }
        __syncthreads();

        const size_t tbase = (size_t)lblk * TILE_ELEMS;
        #pragma unroll
        for (int u = 0; u < 4; ++u) {
            const int ch = (tid + u * 256) * 8;
            *(uint4*)&xnPack[tbase + ch] = *(const uint4*)&Apack[ch];
        }
    }
}

// ---------------------------------------------------------------------------
// k_proj: 5 per-type projections, weight-stationary B in registers.
// (R2 verified version, unchanged.)
// ---------------------------------------------------------------------------
__global__ __launch_bounds__(256) void k_proj(
    const ushort* __restrict__ xnPack, const float* __restrict__ prior,
    const ushort* __restrict__ packW, const float* __restrict__ bEff,
    const float* __restrict__ bk,
    ushort* __restrict__ qw0, ushort* __restrict__ qw1, ushort* __restrict__ kkO,
    ushort* __restrict__ vm0, ushort* __restrict__ vm1)
{
    __shared__ ushort As[8192];   // 16 KB, one A-tile in frag order

    const int tid  = threadIdx.x;
    const int blk  = blockIdx.x;
    const int mat  = blk / 640;
    const int rem  = blk - mat * 640;
    const int bl   = rem >> 5;
    const int sub  = rem & 31;
    const int pg   = sub >> 1;      // 16 groups of 2 tiles
    const int half = sub & 1;       // col half (128 cols)
    const int t    = (int)prior[(size_t)bl * (PP * 3) + 2];

    int slot; const float* bias;
    if (mat < 2)       { slot = t * 2 + mat;           bias = bEff + slot * 256; }
    else if (mat == 2) { slot = 8 + t;                 bias = bk + t * 256; }
    else               { slot = 4 + t * 2 + (mat - 3); bias = bEff + 1024 + (t * 2 + (mat - 3)) * 256; }
    ushort* dst = (mat == 0) ? qw0 : (mat == 1) ? qw1 : (mat == 2) ? kkO : (mat == 3) ? vm0 : vm1;

    const int wv = tid >> 6, lane = tid & 63;

    const ushort* Bp = packW + (size_t)slot * 65536;
    bf16x8 bfr[8][2];
    #pragma unroll
    for (int kt = 0; kt < 8; ++kt)
        #pragma unroll
        for (int nn = 0; nn < 2; ++nn) {
            const int ntg = half * 8 + wv * 2 + nn;
            bfr[kt][nn] = *(const bf16x8*)&Bp[(size_t)((ntg * 8 + kt) * 64 + lane) * 8];
        }

    const int cl = lane & 15, rq = lane >> 4;
    const int colA = half * 128 + wv * 32 + cl;
    const int colB = colA + 16;
    const float biasA = bias[colA], biasB = bias[colB];

    #pragma unroll 1
    for (int tl = 0; tl < 2; ++tl) {
        const int pt = pg * 2 + tl;
        const size_t tbase = (size_t)(bl * 32 + pt) * TILE_ELEMS;
        __syncthreads();   // As reads of previous tile done
        #pragma unroll
        for (int u = 0; u < 4; ++u) {
            const int ch = (tid + u * 256) * 8;
            *(uint4*)&As[ch] = *(const uint4*)&xnPack[tbase + ch];
        }
        __syncthreads();

        f32x4 acc[2][2];
        #pragma unroll
        for (int mt = 0; mt < 2; ++mt)
            #pragma unroll
            for (int nn = 0; nn < 2; ++nn)
                acc[mt][nn] = (f32x4){0.f, 0.f, 0.f, 0.f};

        #pragma unroll
        for (int kt = 0; kt < 8; ++kt) {
            const bf16x8 a0 = *(const bf16x8*)&As[((0 * 8 + kt) * 64 + lane) << 3];
            const bf16x8 a1 = *(const bf16x8*)&As[((1 * 8 + kt) * 64 + lane) << 3];
            acc[0][0] = __builtin_amdgcn_mfma_f32_16x16x32_bf16(a0, bfr[kt][0], acc[0][0], 0, 0, 0);
            acc[0][1] = __builtin_amdgcn_mfma_f32_16x16x32_bf16(a0, bfr[kt][1], acc[0][1], 0, 0, 0);
            acc[1][0] = __builtin_amdgcn_mfma_f32_16x16x32_bf16(a1, bfr[kt][0], acc[1][0], 0, 0, 0);
            acc[1][1] = __builtin_amdgcn_mfma_f32_16x16x32_bf16(a1, bfr[kt][1], acc[1][1], 0, 0, 0);
        }

        const int p0 = pt * 32;
        #pragma unroll
        for (int mt = 0; mt < 2; ++mt) {
            const int row0 = p0 + mt * 16 + rq * 4;
            #pragma unroll
            for (int r2 = 0; r2 < 4; ++r2) {
                const size_t rb = ((size_t)bl * PP + row0 + r2) * II;
                dst[rb + colA] = f2bf(acc[mt][0][r2] + biasA);
                dst[rb + colB] = f2bf(acc[mt][1][r2] + biasB);
            }
        }
    }
}

// ---------------------------------------------------------------------------
// k_attn_out v4: 16-pixel groups (v2's Phase-B efficiency) at 16 waves/CU
// (v3's latency hiding): 256 blocks x 1024 threads, 1 block/CU.
//  Phase A: 16 waves x 1 site each, all 25 Q/K/V ushort4 loads up front.
//  Phase B: 16 waves = 16 col-tiles (ntg = wv); single 8-step MFMA chain
//           per wave -- total MFMA identical to v2 (no duplication).
// ---------------------------------------------------------------------------
__global__ __launch_bounds__(1024) void k_attn_out(
    const ushort* __restrict__ qw0, const ushort* __restrict__ qw1,
    const ushort* __restrict__ kkI,
    const ushort* __restrict__ vm0, const ushort* __restrict__ vm1,
    const int* __restrict__ mask, const float* __restrict__ prior,
    const ushort* __restrict__ packW, const float* __restrict__ ba,
    float* __restrict__ out)
{
    __shared__ ushort aoS[5 * 16 * 264];   // 42.2 KB
    __shared__ float obufF[16 * 260];      // 16.6 KB

    const int tid  = threadIdx.x;
    const int blk  = blockIdx.x;            // 0..255
    const int b    = blk >> 6;
    const int pg   = blk & 63;
    const int p0   = pg * 16;
    const int wv   = tid >> 6, lane = tid & 63;
    const int c0   = lane * 4;

    int ty[5];
    #pragma unroll
    for (int l = 0; l < 5; ++l)
        ty[l] = (int)prior[(size_t)(b * 5 + l) * (PP * 3) + 2];

    // ---- Phase A: 1 site per wave (16 sites), all loads issued up front ----
    {
        const int sl   = wv;                 // local site 0..15
        const int pix  = p0 + sl;
        const int site = b * 1024 + pix;
        const int usite = __builtin_amdgcn_readfirstlane(site);

        ushort4 rq0[5], rq1[5], rkv[5], rv0[5], rv1[5];
        #pragma unroll
        for (int l = 0; l < 5; ++l) {
            const size_t base = (((size_t)(b * 5 + l) << 10) + pix) * II + c0;
            rq0[l] = *(const ushort4*)(qw0 + base);
            rq1[l] = *(const ushort4*)(qw1 + base);
            rkv[l] = *(const ushort4*)(kkI + base);
            rv0[l] = *(const ushort4*)(vm0 + base);
            rv1[l] = *(const ushort4*)(vm1 + base);
        }

        int mv[5][5];
        #pragma unroll
        for (int i = 0; i < 5; ++i)
            #pragma unroll
            for (int j = 0; j < 5; ++j)
                mv[i][j] = mask[(size_t)usite * 25 + i * 5 + j];

        float qf[2][5][4], kf[5][4];
        #pragma unroll
        for (int l = 0; l < 5; ++l) {
            qf[0][l][0] = bf2f(rq0[l].x); qf[0][l][1] = bf2f(rq0[l].y);
            qf[0][l][2] = bf2f(rq0[l].z); qf[0][l][3] = bf2f(rq0[l].w);
            qf[1][l][0] = bf2f(rq1[l].x); qf[1][l][1] = bf2f(rq1[l].y);
            qf[1][l][2] = bf2f(rq1[l].z); qf[1][l][3] = bf2f(rq1[l].w);
            kf[l][0]    = bf2f(rkv[l].x); kf[l][1]    = bf2f(rkv[l].y);
            kf[l][2]    = bf2f(rkv[l].z); kf[l][3]    = bf2f(rkv[l].w);
        }

        float s[5][5];
        #pragma unroll
        for (int j = 0; j < 5; ++j) {
            if (ty[j]) {
                #pragma unroll
                for (int i = 0; i < 5; ++i)
                    s[i][j] = qf[1][i][0] * kf[j][0] + qf[1][i][1] * kf[j][1]
                            + qf[1][i][2] * kf[j][2] + qf[1][i][3] * kf[j][3];
            } else {
                #pragma unroll
                for (int i = 0; i < 5; ++i)
                    s[i][j] = qf[0][i][0] * kf[j][0] + qf[0][i][1] * kf[j][1]
                            + qf[0][i][2] * kf[j][2] + qf[0][i][3] * kf[j][3];
            }
        }
        #pragma unroll
        for (int i = 0; i < 5; ++i)
            #pragma unroll
            for (int j = 0; j < 5; ++j) s[i][j] += __shfl_xor(s[i][j], 1);
        #pragma unroll
        for (int i = 0; i < 5; ++i)
            #pragma unroll
            for (int j = 0; j < 5; ++j) s[i][j] += __shfl_xor(s[i][j], 2);
        #pragma unroll
        for (int i = 0; i < 5; ++i)
            #pragma unroll
            for (int j = 0; j < 5; ++j) s[i][j] += __shfl_xor(s[i][j], 4);

        float vf[2][5][4];
        #pragma unroll
        for (int l = 0; l < 5; ++l) {
            vf[0][l][0] = bf2f(rv0[l].x); vf[0][l][1] = bf2f(rv0[l].y);
            vf[0][l][2] = bf2f(rv0[l].z); vf[0][l][3] = bf2f(rv0[l].w);
            vf[1][l][0] = bf2f(rv1[l].x); vf[1][l][1] = bf2f(rv1[l].y);
            vf[1][l][2] = bf2f(rv1[l].z); vf[1][l][3] = bf2f(rv1[l].w);
        }

        #pragma unroll
        for (int i = 0; i < 5; ++i) {
            float lg[5];
            #pragma unroll
            for (int j = 0; j < 5; ++j)
                lg[j] = mv[i][j] ? s[i][j] * SCALE : -1e9f;
            const float mx = fmaxf(fmaxf(fmaxf(lg[0], lg[1]), fmaxf(lg[2], lg[3])), lg[4]);
            float ex[5], sum = 0.f;
            #pragma unroll
            for (int j = 0; j < 5; ++j) { ex[j] = __expf(lg[j] - mx); sum += ex[j]; }
            const float rs = 1.0f / sum;
            float o0 = 0.f, o1 = 0.f, o2 = 0.f, o3 = 0.f;
            if (ty[i]) {
                #pragma unroll
                for (int j = 0; j < 5; ++j) {
                    o0 += ex[j] * vf[1][j][0]; o1 += ex[j] * vf[1][j][1];
                    o2 += ex[j] * vf[1][j][2]; o3 += ex[j] * vf[1][j][3];
                }
            } else {
                #pragma unroll
                for (int j = 0; j < 5; ++j) {
                    o0 += ex[j] * vf[0][j][0]; o1 += ex[j] * vf[0][j][1];
                    o2 += ex[j] * vf[0][j][2]; o3 += ex[j] * vf[0][j][3];
                }
            }
            o0 *= rs; o1 *= rs; o2 *= rs; o3 *= rs;
            uint2 w2;
            w2.x = (unsigned)f2bf(o0) | ((unsigned)f2bf(o1) << 16);
            w2.y = (unsigned)f2bf(o2) | ((unsigned)f2bf(o3) << 16);
            *(uint2*)&aoS[(i * 16 + sl) * 264 + c0] = w2;
        }
    }
    __syncthreads();

    // ---- Phase B: 16 waves = 16 col-tiles ----
    const int ntg  = wv;                        // col-tile 0..15
    const int cl = lane & 15, rq = lane >> 4;
    const int rowA = lane & 15;                 // A-frag row
    const int ksub = rq * 8;                    // A-frag k-subgroup
    const int colG = ntg * 16 + cl;             // global col 0..255

    #pragma unroll 1
    for (int l = 0; l < 5; ++l) {
        const int t = ty[l];
        const ushort* Bp = packW + (size_t)(10 + t) * 65536;
        bf16x8 bfr[8];
        #pragma unroll
        for (int kt = 0; kt < 8; ++kt)
            bfr[kt] = *(const bf16x8*)&Bp[(size_t)((ntg * 8 + kt) * 64 + lane) * 8];

        f32x4 acc = (f32x4){0.f, 0.f, 0.f, 0.f};
        const ushort* aRow = &aoS[(l * 16 + rowA) * 264 + ksub];
        #pragma unroll
        for (int kt = 0; kt < 8; ++kt) {
            const bf16x8 a0 = *(const bf16x8*)(aRow + kt * 32);
            acc = __builtin_amdgcn_mfma_f32_16x16x32_bf16(a0, bfr[kt], acc, 0, 0, 0);
        }

        const float bias = ba[t * CC + colG];

        __syncthreads();   // previous l's obuf reads done
        #pragma unroll
        for (int r2 = 0; r2 < 4; ++r2)
            obufF[(rq * 4 + r2) * 260 + colG] = acc[r2] + bias;
        __syncthreads();

        // coalesced store: 16 rows x 64 float4-chunks = 1024 stores (1/thread)
        const int row = tid >> 6;               // 0..15
        const int ch  = (tid & 63) * 4;         // float4 chunk within 256 cols
        const float4 v4 = *(const float4*)&obufF[row * 260 + ch];
        *(float4*)(out + ((size_t)(b * LL + l) * PP + p0 + row) * CC + ch) = v4;
    }
}

// ---------------------------------------------------------------------------
extern "C" void kernel_launch(void* const* d_in, const int* in_sizes, int n_in,
                              void* d_out, int out_size, void* d_ws, size_t ws_size,
                              hipStream_t stream) {
    const float* x       = (const float*)d_in[0];
    const int*   mask    = (const int*)d_in[1];
    const float* prior   = (const float*)d_in[2];
    const float* lnw     = (const float*)d_in[3];
    const float* lnb     = (const float*)d_in[4];
    const float* Wq      = (const float*)d_in[5];
    const float* bq      = (const float*)d_in[6];
    const float* Wk      = (const float*)d_in[7];
    const float* bk      = (const float*)d_in[8];
    const float* Wv      = (const float*)d_in[9];
    const float* bv      = (const float*)d_in[10];
    const float* Wa      = (const float*)d_in[11];
    const float* ba      = (const float*)d_in[12];
    const float* rel_att = (const float*)d_in[13];
    const float* rel_msg = (const float*)d_in[14];
    float* out = (float*)d_out;

    ushort* qw0    = (ushort*)d_ws;
    ushort* qw1    = qw0 + NTOK;
    ushort* kko    = qw1 + NTOK;
    ushort* vm0    = kko + NTOK;
    ushort* vm1    = vm0 + NTOK;
    ushort* xnPack = vm1 + NTOK;
    ushort* packW  = xnPack + NTOK;                 // 12 * 65536 bf16
    float*  bEff   = (float*)(packW + 12 * 65536);  // 2048 fp32

    hipLaunchKernelGGL(k_fold, dim3(832), dim3(256), 0, stream,
                       Wq, Wv, Wk, Wa, bq, bv, rel_att, rel_msg,
                       x, lnw, lnb, packW, bEff, xnPack);
    hipLaunchKernelGGL(k_proj, dim3(3200), dim3(256), 0, stream,
                       xnPack, prior, packW, bEff, bk, qw0, qw1, kko, vm0, vm1);
    hipLaunchKernelGGL(k_attn_out, dim3(256), dim3(1024), 0, stream,
                       qw0, qw1, kko, vm0, vm1, mask, prior, packW, ba, out);
}

// Round 12
// 149.181 us; speedup vs baseline: 1.3982x; 1.0169x over previous
//
#include <hip/hip_runtime.h>
#include <hip/hip_bf16.h>
#include <math.h>

#define BB 4
#define LL 5
#define HSZ 32
#define WSZ 32
#define PP (HSZ*WSZ)   // 1024
#define CC 256
#define MM 8
#define DD 32
#define II 256
#define TT 2
#define NTOK (BB*PP*LL*II)   // 5,242,880
#define TILE_ELEMS 8192      // 32 pixels x 256 chans, bf16 ELEMENTS (16 KB)
#define SCALE 0.17677669529663687f  // 1/sqrt(32)

typedef short bf16x8 __attribute__((ext_vector_type(8)));
typedef float f32x4 __attribute__((ext_vector_type(4)));

static __device__ __forceinline__ ushort f2bf(float f) {
    unsigned u = __float_as_uint(f);
    unsigned r = (u + 0x7fffu + ((u >> 16) & 1u)) >> 16;   // RNE
    return (ushort)r;
}
static __device__ __forceinline__ float bf2f(ushort u) {
    return __uint_as_float(((unsigned)u) << 16);
}

// ---------------------------------------------------------------------------
// k_fold: merged weight-prep + LayerNorm/pack (R2 verified; measured ~13 us).
// ---------------------------------------------------------------------------
__global__ __launch_bounds__(256) void k_fold(
    const float* __restrict__ Wq, const float* __restrict__ Wv,
    const float* __restrict__ Wk, const float* __restrict__ Wa,
    const float* __restrict__ bq, const float* __restrict__ bv,
    const float* __restrict__ rel_att, const float* __restrict__ rel_msg,
    const float* __restrict__ x,
    const float* __restrict__ lnw, const float* __restrict__ lnb,
    ushort* __restrict__ packW, float* __restrict__ bEff,
    ushort* __restrict__ xnPack)
{
    __shared__ float As[1024];
    __shared__ ushort Apack[8192];
    const int blk = blockIdx.x;
    const int tid = threadIdx.x;

    if (blk < 64) {
        const int p  = blk >> 5;
        const int t  = (blk >> 4) & 1;
        const int ts = (blk >> 3) & 1;
        const int m  = blk & 7;
        const float* A = (p == 0)
            ? rel_att + (size_t)((t * 2 + ts) * 8 + m) * 1024
            : rel_msg + (size_t)((ts * 2 + t) * 8 + m) * 1024;
        for (int i = tid; i < 1024; i += 256) As[i] = A[i];
        __syncthreads();

        const float* W = ((p == 0) ? Wq : Wv) + (size_t)t * 65536;
        const int k = tid;
        float wrow[32];
        #pragma unroll
        for (int u = 0; u < 8; ++u)
            *(float4*)&wrow[u * 4] = *(const float4*)&W[k * 256 + m * 32 + u * 4];

        const int slot = (p == 0 ? 0 : 4) + t * 2 + ts;
        ushort* base = packW + (size_t)slot * 65536;
        const int kt = k >> 5, j = k & 7, lq = ((k >> 3) & 3) * 16;
        #pragma unroll
        for (int q = 0; q < 32; ++q) {
            float acc = 0.f;
            #pragma unroll
            for (int pp = 0; pp < 32; ++pp) acc += wrow[pp] * As[pp * 32 + q];
            const int nt = m * 2 + (q >> 4);
            const int lane = lq + (q & 15);
            base[(size_t)((nt * 8 + kt) * 64 + lane) * 8 + j] = f2bf(acc);
        }
        if (tid < 32) {
            const int q = tid;
            const float* bi = ((p == 0) ? bq : bv) + t * 256 + m * 32;
            float acc = 0.f;
            #pragma unroll
            for (int pp = 0; pp < 32; ++pp) acc += bi[pp] * As[pp * 32 + q];
            bEff[(p ? 1024 : 0) + (t * 2 + ts) * 256 + m * 32 + q] = acc;
        }
    } else if (blk < 192) {
        const int idx = blk - 64;
        const int which = idx >> 6;              // 0 = Wk, 1 = Wa
        const int gi = (idx & 63) * 256 + tid;   // 0..16383
        const int t = gi >> 13;
        const int sub = gi & 8191;
        const float* src = ((which == 0) ? Wk : Wa) + (size_t)t * 65536;
        const int slot = (which == 0 ? 8 : 10) + t;
        const int nt = sub >> 9, kt = (sub >> 6) & 7, lane = sub & 63;
        const int k0 = kt * 32 + (lane >> 4) * 8;
        const int n  = nt * 16 + (lane & 15);
        ushort h[8];
        #pragma unroll
        for (int j = 0; j < 8; ++j) h[j] = f2bf(src[(size_t)(k0 + j) * 256 + n]);
        uint4 o;
        o.x = (unsigned)h[0] | ((unsigned)h[1] << 16);
        o.y = (unsigned)h[2] | ((unsigned)h[3] << 16);
        o.z = (unsigned)h[4] | ((unsigned)h[5] << 16);
        o.w = (unsigned)h[6] | ((unsigned)h[7] << 16);
        *(uint4*)(packW + (size_t)slot * 65536 + (size_t)sub * 8) = o;
    } else {
        const int lblk = blk - 192;
        const int bl  = lblk >> 5;
        const int pt  = lblk & 31;
        const int p0  = pt * 32;

        const int r  = tid >> 3;     // 0..31 pixel row
        const int jj = tid & 7;      // 8 threads/row, 32 chans each
        const float* xrow = x + ((size_t)bl * PP + p0 + r) * CC;
        float4 xv[8];
        float s1 = 0.f, s2 = 0.f;
        #pragma unroll
        for (int u = 0; u < 8; ++u) {
            xv[u] = *(const float4*)(xrow + jj * 32 + u * 4);
            s1 += xv[u].x + xv[u].y + xv[u].z + xv[u].w;
            s2 += xv[u].x * xv[u].x + xv[u].y * xv[u].y + xv[u].z * xv[u].z + xv[u].w * xv[u].w;
        }
        s1 += __shfl_xor(s1, 1); s1 += __shfl_xor(s1, 2); s1 += __shfl_xor(s1, 4);
        s2 += __shfl_xor(s2, 1); s2 += __shfl_xor(s2, 2); s2 += __shfl_xor(s2, 4);
        const float mu   = s1 * (1.0f / 256.0f);
        const float var  = s2 * (1.0f / 256.0f) - mu * mu;
        const float rstd = rsqrtf(var + 1e-5f);

        const int mt_r = r >> 4, rm = r & 15;
        #pragma unroll
        for (int u = 0; u < 8; ++u) {
            const int c0 = jj * 32 + u * 4;
            const float4 g  = *(const float4*)(lnw + c0);
            const float4 bt = *(const float4*)(lnb + c0);
            const ushort h0 = f2bf((xv[u].x - mu) * rstd * g.x + bt.x);
            const ushort h1 = f2bf((xv[u].y - mu) * rstd * g.y + bt.y);
            const ushort h2 = f2bf((xv[u].z - mu) * rstd * g.z + bt.z);
            const ushort h3 = f2bf((xv[u].w - mu) * rstd * g.w + bt.w);
            uint2 w2;
            w2.x = (unsigned)h0 | ((unsigned)h1 << 16);
            w2.y = (unsigned)h2 | ((unsigned)h3 << 16);
            const int kt   = c0 >> 5;
            const int lsub = rm + (((c0 >> 3) & 3) << 4);
            const int j0   = c0 & 7;
            *(uint2*)&Apack[(((mt_r * 8 + kt) * 64 + lsub) << 3) + j0] = w2;
        }
        __syncthreads();

        const size_t tbase = (size_t)lblk * TILE_ELEMS;
        #pragma unroll
        for (int u = 0; u < 4; ++u) {
            const int ch = (tid + u * 256) * 8;
            *(uint4*)&xnPack[tbase + ch] = *(const uint4*)&Apack[ch];
        }
    }
}

// ---------------------------------------------------------------------------
// k_proj: 5 per-type projections, weight-stationary B in registers.
// (R2 verified version; measured ~6 us.)
// ---------------------------------------------------------------------------
__global__ __launch_bounds__(256) void k_proj(
    const ushort* __restrict__ xnPack, const float* __restrict__ prior,
    const ushort* __restrict__ packW, const float* __restrict__ bEff,
    const float* __restrict__ bk,
    ushort* __restrict__ qw0, ushort* __restrict__ qw1, ushort* __restrict__ kkO,
    ushort* __restrict__ vm0, ushort* __restrict__ vm1)
{
    __shared__ ushort As[8192];   // 16 KB, one A-tile in frag order

    const int tid  = threadIdx.x;
    const int blk  = blockIdx.x;
    const int mat  = blk / 640;
    const int rem  = blk - mat * 640;
    const int bl   = rem >> 5;
    const int sub  = rem & 31;
    const int pg   = sub >> 1;      // 16 groups of 2 tiles
    const int half = sub & 1;       // col half (128 cols)
    const int t    = (int)prior[(size_t)bl * (PP * 3) + 2];

    int slot; const float* bias;
    if (mat < 2)       { slot = t * 2 + mat;           bias = bEff + slot * 256; }
    else if (mat == 2) { slot = 8 + t;                 bias = bk + t * 256; }
    else               { slot = 4 + t * 2 + (mat - 3); bias = bEff + 1024 + (t * 2 + (mat - 3)) * 256; }
    ushort* dst = (mat == 0) ? qw0 : (mat == 1) ? qw1 : (mat == 2) ? kkO : (mat == 3) ? vm0 : vm1;

    const int wv = tid >> 6, lane = tid & 63;

    const ushort* Bp = packW + (size_t)slot * 65536;
    bf16x8 bfr[8][2];
    #pragma unroll
    for (int kt = 0; kt < 8; ++kt)
        #pragma unroll
        for (int nn = 0; nn < 2; ++nn) {
            const int ntg = half * 8 + wv * 2 + nn;
            bfr[kt][nn] = *(const bf16x8*)&Bp[(size_t)((ntg * 8 + kt) * 64 + lane) * 8];
        }

    const int cl = lane & 15, rq = lane >> 4;
    const int colA = half * 128 + wv * 32 + cl;
    const int colB = colA + 16;
    const float biasA = bias[colA], biasB = bias[colB];

    #pragma unroll 1
    for (int tl = 0; tl < 2; ++tl) {
        const int pt = pg * 2 + tl;
        const size_t tbase = (size_t)(bl * 32 + pt) * TILE_ELEMS;
        __syncthreads();   // As reads of previous tile done
        #pragma unroll
        for (int u = 0; u < 4; ++u) {
            const int ch = (tid + u * 256) * 8;
            *(uint4*)&As[ch] = *(const uint4*)&xnPack[tbase + ch];
        }
        __syncthreads();

        f32x4 acc[2][2];
        #pragma unroll
        for (int mt = 0; mt < 2; ++mt)
            #pragma unroll
            for (int nn = 0; nn < 2; ++nn)
                acc[mt][nn] = (f32x4){0.f, 0.f, 0.f, 0.f};

        #pragma unroll
        for (int kt = 0; kt < 8; ++kt) {
            const bf16x8 a0 = *(const bf16x8*)&As[((0 * 8 + kt) * 64 + lane) << 3];
            const bf16x8 a1 = *(const bf16x8*)&As[((1 * 8 + kt) * 64 + lane) << 3];
            acc[0][0] = __builtin_amdgcn_mfma_f32_16x16x32_bf16(a0, bfr[kt][0], acc[0][0], 0, 0, 0);
            acc[0][1] = __builtin_amdgcn_mfma_f32_16x16x32_bf16(a0, bfr[kt][1], acc[0][1], 0, 0, 0);
            acc[1][0] = __builtin_amdgcn_mfma_f32_16x16x32_bf16(a1, bfr[kt][0], acc[1][0], 0, 0, 0);
            acc[1][1] = __builtin_amdgcn_mfma_f32_16x16x32_bf16(a1, bfr[kt][1], acc[1][1], 0, 0, 0);
        }

        const int p0 = pt * 32;
        #pragma unroll
        for (int mt = 0; mt < 2; ++mt) {
            const int row0 = p0 + mt * 16 + rq * 4;
            #pragma unroll
            for (int r2 = 0; r2 < 4; ++r2) {
                const size_t rb = ((size_t)bl * PP + row0 + r2) * II;
                dst[rb + colA] = f2bf(acc[mt][0][r2] + biasA);
                dst[rb + colB] = f2bf(acc[mt][1][r2] + biasB);
            }
        }
    }
}

// ---------------------------------------------------------------------------
// k_attn_out v2: merged col-halves -- 256 blocks x 512 threads (8 waves).
// (R7 best-measured version, restored verbatim: 149.3 us total.)
// ---------------------------------------------------------------------------
__global__ __launch_bounds__(512) void k_attn_out(
    const ushort* __restrict__ qw0, const ushort* __restrict__ qw1,
    const ushort* __restrict__ kkI,
    const ushort* __restrict__ vm0, const ushort* __restrict__ vm1,
    const int* __restrict__ mask, const float* __restrict__ prior,
    const ushort* __restrict__ packW, const float* __restrict__ ba,
    float* __restrict__ out)
{
    __shared__ ushort aoS[5 * 16 * 264];   // 42.2 KB
    __shared__ float obufF[16 * 260];      // 16.6 KB

    const int tid  = threadIdx.x;
    const int blk  = blockIdx.x;            // 0..255
    const int b    = blk >> 6;
    const int pg   = blk & 63;
    const int p0   = pg * 16;
    const int wv   = tid >> 6, lane = tid & 63;
    const int c0   = lane * 4;

    int ty[5];
    #pragma unroll
    for (int l = 0; l < 5; ++l)
        ty[l] = (int)prior[(size_t)(b * 5 + l) * (PP * 3) + 2];

    // ---- Phase A: 2 sites per wave, all loads issued up front ----
    {
        ushort4 rq0[2][5], rq1[2][5], rkv[2][5], rv0[2][5], rv1[2][5];
        #pragma unroll
        for (int it = 0; it < 2; ++it) {
            const int pix = p0 + wv * 2 + it;
            #pragma unroll
            for (int l = 0; l < 5; ++l) {
                const size_t base = (((size_t)(b * 5 + l) << 10) + pix) * II + c0;
                rq0[it][l] = *(const ushort4*)(qw0 + base);
                rq1[it][l] = *(const ushort4*)(qw1 + base);
                rkv[it][l] = *(const ushort4*)(kkI + base);
                rv0[it][l] = *(const ushort4*)(vm0 + base);
                rv1[it][l] = *(const ushort4*)(vm1 + base);
            }
        }

        #pragma unroll
        for (int it = 0; it < 2; ++it) {
            const int sl   = wv * 2 + it;
            const int pix  = p0 + sl;
            const int site = b * 1024 + pix;
            const int usite = __builtin_amdgcn_readfirstlane(site);

            int mv[5][5];
            #pragma unroll
            for (int i = 0; i < 5; ++i)
                #pragma unroll
                for (int j = 0; j < 5; ++j)
                    mv[i][j] = mask[(size_t)usite * 25 + i * 5 + j];

            float qf[2][5][4], kf[5][4];
            #pragma unroll
            for (int l = 0; l < 5; ++l) {
                qf[0][l][0] = bf2f(rq0[it][l].x); qf[0][l][1] = bf2f(rq0[it][l].y);
                qf[0][l][2] = bf2f(rq0[it][l].z); qf[0][l][3] = bf2f(rq0[it][l].w);
                qf[1][l][0] = bf2f(rq1[it][l].x); qf[1][l][1] = bf2f(rq1[it][l].y);
                qf[1][l][2] = bf2f(rq1[it][l].z); qf[1][l][3] = bf2f(rq1[it][l].w);
                kf[l][0]    = bf2f(rkv[it][l].x); kf[l][1]    = bf2f(rkv[it][l].y);
                kf[l][2]    = bf2f(rkv[it][l].z); kf[l][3]    = bf2f(rkv[it][l].w);
            }

            float s[5][5];
            #pragma unroll
            for (int j = 0; j < 5; ++j) {
                if (ty[j]) {
                    #pragma unroll
                    for (int i = 0; i < 5; ++i)
                        s[i][j] = qf[1][i][0] * kf[j][0] + qf[1][i][1] * kf[j][1]
                                + qf[1][i][2] * kf[j][2] + qf[1][i][3] * kf[j][3];
                } else {
                    #pragma unroll
                    for (int i = 0; i < 5; ++i)
                        s[i][j] = qf[0][i][0] * kf[j][0] + qf[0][i][1] * kf[j][1]
                                + qf[0][i][2] * kf[j][2] + qf[0][i][3] * kf[j][3];
                }
            }
            #pragma unroll
            for (int i = 0; i < 5; ++i)
                #pragma unroll
                for (int j = 0; j < 5; ++j) s[i][j] += __shfl_xor(s[i][j], 1);
            #pragma unroll
            for (int i = 0; i < 5; ++i)
                #pragma unroll
                for (int j = 0; j < 5; ++j) s[i][j] += __shfl_xor(s[i][j], 2);
            #pragma unroll
            for (int i = 0; i < 5; ++i)
                #pragma unroll
                for (int j = 0; j < 5; ++j) s[i][j] += __shfl_xor(s[i][j], 4);

            float vf[2][5][4];
            #pragma unroll
            for (int l = 0; l < 5; ++l) {
                vf[0][l][0] = bf2f(rv0[it][l].x); vf[0][l][1] = bf2f(rv0[it][l].y);
                vf[0][l][2] = bf2f(rv0[it][l].z); vf[0][l][3] = bf2f(rv0[it][l].w);
                vf[1][l][0] = bf2f(rv1[it][l].x); vf[1][l][1] = bf2f(rv1[it][l].y);
                vf[1][l][2] = bf2f(rv1[it][l].z); vf[1][l][3] = bf2f(rv1[it][l].w);
            }

            #pragma unroll
            for (int i = 0; i < 5; ++i) {
                float lg[5];
                #pragma unroll
                for (int j = 0; j < 5; ++j)
                    lg[j] = mv[i][j] ? s[i][j] * SCALE : -1e9f;
                const float mx = fmaxf(fmaxf(fmaxf(lg[0], lg[1]), fmaxf(lg[2], lg[3])), lg[4]);
                float ex[5], sum = 0.f;
                #pragma unroll
                for (int j = 0; j < 5; ++j) { ex[j] = __expf(lg[j] - mx); sum += ex[j]; }
                const float rs = 1.0f / sum;
                float o0 = 0.f, o1 = 0.f, o2 = 0.f, o3 = 0.f;
                if (ty[i]) {
                    #pragma unroll
                    for (int j = 0; j < 5; ++j) {
                        o0 += ex[j] * vf[1][j][0]; o1 += ex[j] * vf[1][j][1];
                        o2 += ex[j] * vf[1][j][2]; o3 += ex[j] * vf[1][j][3];
                    }
                } else {
                    #pragma unroll
                    for (int j = 0; j < 5; ++j) {
                        o0 += ex[j] * vf[0][j][0]; o1 += ex[j] * vf[0][j][1];
                        o2 += ex[j] * vf[0][j][2]; o3 += ex[j] * vf[0][j][3];
                    }
                }
                o0 *= rs; o1 *= rs; o2 *= rs; o3 *= rs;
                uint2 w2;
                w2.x = (unsigned)f2bf(o0) | ((unsigned)f2bf(o1) << 16);
                w2.y = (unsigned)f2bf(o2) | ((unsigned)f2bf(o3) << 16);
                *(uint2*)&aoS[(i * 16 + sl) * 264 + c0] = w2;
            }
        }
    }
    __syncthreads();

    // ---- Phase B: 8 waves = 2 halves x 4 col-roles ----
    const int half = wv >> 2;
    const int wv2  = wv & 3;
    const int cl = lane & 15, rq = lane >> 4;
    const int rowA = lane & 15;
    const int ksub = (lane >> 4) * 8;
    const int colL_A = wv2 * 32 + cl;           // local col within the 128-half
    const int colL_B = colL_A + 16;

    #pragma unroll 1
    for (int l = 0; l < 5; ++l) {
        const int t = ty[l];
        const ushort* Bp = packW + (size_t)(10 + t) * 65536;
        bf16x8 bfr[8][2];
        #pragma unroll
        for (int kt = 0; kt < 8; ++kt)
            #pragma unroll
            for (int nn = 0; nn < 2; ++nn) {
                const int ntg = half * 8 + wv2 * 2 + nn;
                bfr[kt][nn] = *(const bf16x8*)&Bp[(size_t)((ntg * 8 + kt) * 64 + lane) * 8];
            }

        f32x4 acc[2];
        acc[0] = (f32x4){0.f, 0.f, 0.f, 0.f};
        acc[1] = (f32x4){0.f, 0.f, 0.f, 0.f};

        const ushort* aRow = &aoS[(l * 16 + rowA) * 264 + ksub];
        #pragma unroll
        for (int kt = 0; kt < 8; ++kt) {
            const bf16x8 a0 = *(const bf16x8*)(aRow + kt * 32);
            acc[0] = __builtin_amdgcn_mfma_f32_16x16x32_bf16(a0, bfr[kt][0], acc[0], 0, 0, 0);
            acc[1] = __builtin_amdgcn_mfma_f32_16x16x32_bf16(a0, bfr[kt][1], acc[1], 0, 0, 0);
        }

        const float biasA = ba[t * CC + half * 128 + colL_A];
        const float biasB = ba[t * CC + half * 128 + colL_B];

        __syncthreads();   // previous l's obuf reads done
        #pragma unroll
        for (int r2 = 0; r2 < 4; ++r2) {
            obufF[(rq * 4 + r2) * 260 + half * 128 + colL_A] = acc[0][r2] + biasA;
            obufF[(rq * 4 + r2) * 260 + half * 128 + colL_B] = acc[1][r2] + biasB;
        }
        __syncthreads();

        // coalesced store: 16 rows x 64 float4-chunks = 1024 stores
        #pragma unroll
        for (int k2 = 0; k2 < 2; ++k2) {
            const int id  = tid + k2 * 512;
            const int row = id >> 6;            // 0..15
            const int ch  = (id & 63) * 4;      // float4 chunk within 256 cols
            const float4 v4 = *(const float4*)&obufF[row * 260 + ch];
            *(float4*)(out + ((size_t)(b * LL + l) * PP + p0 + row) * CC + ch) = v4;
        }
    }
}

// ---------------------------------------------------------------------------
extern "C" void kernel_launch(void* const* d_in, const int* in_sizes, int n_in,
                              void* d_out, int out_size, void* d_ws, size_t ws_size,
                              hipStream_t stream) {
    const float* x       = (const float*)d_in[0];
    const int*   mask    = (const int*)d_in[1];
    const float* prior   = (const float*)d_in[2];
    const float* lnw     = (const float*)d_in[3];
    const float* lnb     = (const float*)d_in[4];
    const float* Wq      = (const float*)d_in[5];
    const float* bq      = (const float*)d_in[6];
    const float* Wk      = (const float*)d_in[7];
    const float* bk      = (const float*)d_in[8];
    const float* Wv      = (const float*)d_in[9];
    const float* bv      = (const float*)d_in[10];
    const float* Wa      = (const float*)d_in[11];
    const float* ba      = (const float*)d_in[12];
    const float* rel_att = (const float*)d_in[13];
    const float* rel_msg = (const float*)d_in[14];
    float* out = (float*)d_out;

    ushort* qw0    = (ushort*)d_ws;
    ushort* qw1    = qw0 + NTOK;
    ushort* kko    = qw1 + NTOK;
    ushort* vm0    = kko + NTOK;
    ushort* vm1    = vm0 + NTOK;
    ushort* xnPack = vm1 + NTOK;
    ushort* packW  = xnPack + NTOK;                 // 12 * 65536 bf16
    float*  bEff   = (float*)(packW + 12 * 65536);  // 2048 fp32

    hipLaunchKernelGGL(k_fold, dim3(832), dim3(256), 0, stream,
                       Wq, Wv, Wk, Wa, bq, bv, rel_att, rel_msg,
                       x, lnw, lnb, packW, bEff, xnPack);
    hipLaunchKernelGGL(k_proj, dim3(3200), dim3(256), 0, stream,
                       xnPack, prior, packW, bEff, bk, qw0, qw1, kko, vm0, vm1);
    hipLaunchKernelGGL(k_attn_out, dim3(256), dim3(512), 0, stream,
                       qw0, qw1, kko, vm0, vm1, mask, prior, packW, ba, out);
}